// Round 5
// baseline (214.150 us; speedup 1.0000x reference)
//
#include <hip/hip_runtime.h>

typedef __attribute__((ext_vector_type(8))) short short8;
typedef __attribute__((ext_vector_type(4))) float f32x4;
typedef __attribute__((ext_vector_type(2))) float f32x2;
typedef __attribute__((ext_vector_type(4))) unsigned int u32x4;

#define NNODES 200
#define NEDGE  8000
#define NF1    8192
#define NH     2048
#define NCL    512
#define K1     24576
#define K2     6144
#define MR     512      // padded rows (2 graphs * 200 -> 400 valid)
#define MV     400
#define PV     400      // P partial row stride (valid rows only)
#define KC1    16
#define BK1    1536
#define KC2    16
#define BK2    384

// ---------------- workspace layout (bytes) ----------------
#define OFF_P1  0ull
#define SZ_P1   (16ull*PV*NH*4)            // 52,428,800
#define OFF_P2  (OFF_P1 + SZ_P1)
#define SZ_P2   (16ull*PV*NCL*4)           // 13,107,200
#define OFF_A1  (OFF_P2 + SZ_P2)           // 65,536,000
#define SZ_A1   ((unsigned long long)MR*K1*2)  // 25,165,824
#define OFF_A2  (OFF_A1 + SZ_A1)           // 90,701,824
#define SZ_A2   ((unsigned long long)MR*K2*2)  // 6,291,456
#define OFF_DEG (OFF_A2 + SZ_A2)           // 96,993,280
#define OFF_LD  (OFF_DEG + 2048)
#define OFF_LL  (OFF_LD + 320000ull)       // LL: 2*512*224*2 = 458,752
// zt (classifier input, 2*512*200*4 = 819,200 B) reuses the P1 region (dead by then)
#define OFF_Z   OFF_P1

static __device__ __forceinline__ unsigned short f2bf(float f) {
  unsigned int u = __float_as_uint(f);
  unsigned int r = (u + 0x7fffu + ((u >> 16) & 1u)) >> 16;
  return (unsigned short)r;
}
static __device__ __forceinline__ unsigned packbf(float a, float b) {
  return (unsigned)f2bf(a) | ((unsigned)f2bf(b) << 16);
}

// ---------------- zero scratch regions ----------------
__global__ void k_zero(f32x4* p1, int n1, f32x4* p2, int n2, f32x4* p3, int n3) {
  int i = blockIdx.x * 256 + threadIdx.x;
  f32x4 z = {0.f, 0.f, 0.f, 0.f};
  if (i < n1) p1[i] = z;
  i -= n1;
  if (i >= 0 && i < n2) p2[i] = z;
  i -= n2;
  if (i >= 0 && i < n3) p3[i] = z;
}

__global__ void k_deg(const int* __restrict__ ei1, const float* __restrict__ ew1,
                      const int* __restrict__ ei2, const float* __restrict__ ew2,
                      float* __restrict__ deg) {
  int e = blockIdx.x * 256 + threadIdx.x;
  if (e >= 2 * NEDGE) return;
  int g = e / NEDGE, k = e % NEDGE;
  const int* ei = g ? ei2 : ei1;
  const float* ew = g ? ew2 : ew1;
  atomicAdd(deg + g * NNODES + ei[k], ew[k]);
}

__global__ void k_buildL(const int* __restrict__ ei1, const float* __restrict__ ew1,
                         const int* __restrict__ ei2, const float* __restrict__ ew2,
                         const float* __restrict__ deg, float* __restrict__ Ld) {
  int e = blockIdx.x * 256 + threadIdx.x;
  if (e >= 2 * NEDGE) return;
  int g = e / NEDGE, k = e % NEDGE;
  const int* ei = g ? ei2 : ei1;
  const float* ew = g ? ew2 : ew1;
  int r = ei[k], c = ei[NEDGE + k];
  float dr = deg[g * NNODES + r], dc = deg[g * NNODES + c];
  float ir = dr > 0.f ? 1.0f / sqrtf(dr) : 0.f;
  float ic = dc > 0.f ? 1.0f / sqrtf(dc) : 0.f;
  float nrm = -ir * ew[k] * ic;
  atomicAdd(Ld + ((size_t)g * NNODES + c) * NNODES + r, nrm);
}

// LL rows [0,200): L ; rows [200,400): 2L^2-I   (bf16, stride 224, 512-row panels)
__global__ void k_LL(const float* __restrict__ Ld, unsigned short* __restrict__ LLb) {
  int b = blockIdx.x;
  int g = b / NNODES, i = b % NNODES;
  __shared__ float Lr[NNODES];
  const float* Lg = Ld + (size_t)g * NNODES * NNODES;
  int t = threadIdx.x;
  if (t < NNODES) Lr[t] = Lg[i * NNODES + t];
  __syncthreads();
  if (t < NNODES) {
    float acc = 0.f;
    for (int k = 0; k < NNODES; ++k) acc = fmaf(Lr[k], Lg[k * NNODES + t], acc);
    unsigned short* LLg = LLb + (size_t)g * MR * 224;
    LLg[(size_t)i * 224 + t] = f2bf(Lr[t]);
    LLg[(size_t)(NNODES + i) * 224 + t] = f2bf(2.f * acc - (i == t ? 1.f : 0.f));
  }
}

__global__ void k_t0(const float* __restrict__ x1, const float* __restrict__ x2,
                     unsigned short* __restrict__ A1) {
  int gid = blockIdx.x * 256 + threadIdx.x;
  int row = gid / (NF1 / 8);
  int c8 = (gid % (NF1 / 8)) * 8;
  const float* xp = (row < NNODES ? x1 + (size_t)row * NF1
                                  : x2 + (size_t)(row - NNODES) * NF1) + c8;
  f32x4 a = *(const f32x4*)xp;
  f32x4 b = *(const f32x4*)(xp + 4);
  u32x4 o;
  o[0] = packbf(a[0], a[1]);
  o[1] = packbf(a[2], a[3]);
  o[2] = packbf(b[0], b[1]);
  o[3] = packbf(b[2], b[3]);
  *(u32x4*)(A1 + (size_t)row * K1 + c8) = o;
}

// builds T1/T2 column blocks:  [T1;T2](:, nt*64..) = LL @ T0(:, nt*64..)
__global__ __launch_bounds__(256, 1)
void k_abuild(const unsigned short* __restrict__ LLb, const unsigned short* __restrict__ Asrc,
              unsigned short* __restrict__ Adst, const int Nf, const int Ka) {
  __shared__ __align__(16) unsigned short XF[7][4][64][8];
  const int g = blockIdx.x & 1;
  const int nt = blockIdx.x >> 1;
  const int nbase = nt * 64;
  const int t = threadIdx.x;

  #pragma unroll
  for (int it = 0; it < 14; ++it) {
    const int pos = it * 256 + t;
    const int j = pos >> 4;
    const int n4 = (pos & 15) * 4;
    unsigned long long v = 0ull;
    if (j < NNODES)
      v = *(const unsigned long long*)(Asrc + (size_t)(g * NNODES + j) * Ka + nbase + n4);
    const int ks = j >> 5, kg = (j >> 3) & 3, jj = j & 7;
    #pragma unroll
    for (int e = 0; e < 4; ++e) {
      const int nn = n4 + e;
      XF[ks][nn >> 4][(nn & 15) + 16 * kg][jj] = (unsigned short)(v >> (16 * e));
    }
  }
  __syncthreads();

  const int w = t >> 6, lane = t & 63;
  const int lm = lane & 15, lk8 = (lane >> 4) * 8;
  f32x4 acc[7][4];
  #pragma unroll
  for (int i = 0; i < 7; ++i)
    #pragma unroll
    for (int j = 0; j < 4; ++j) acc[i][j] = (f32x4){0.f, 0.f, 0.f, 0.f};

  const unsigned short* LLg = LLb + (size_t)g * MR * 224;
  #pragma unroll
  for (int ks = 0; ks < 7; ++ks) {
    short8 bfr[4];
    #pragma unroll
    for (int nf = 0; nf < 4; ++nf) bfr[nf] = *(const short8*)&XF[ks][nf][lane][0];
    short8 af[7];
    #pragma unroll
    for (int mf = 0; mf < 7; ++mf)
      af[mf] = *(const short8*)(LLg + (size_t)(w * 112 + mf * 16 + lm) * 224 + ks * 32 + lk8);
    #pragma unroll
    for (int mf = 0; mf < 7; ++mf)
      #pragma unroll
      for (int nf = 0; nf < 4; ++nf)
        acc[mf][nf] = __builtin_amdgcn_mfma_f32_16x16x32_bf16(af[mf], bfr[nf], acc[mf][nf], 0, 0, 0);
  }

  const int lr4 = (lane >> 4) * 4;
  #pragma unroll
  for (int mf = 0; mf < 7; ++mf) {
    #pragma unroll
    for (int ri = 0; ri < 4; ++ri) {
      const int m = w * 112 + mf * 16 + lr4 + ri;
      if (m < MV) {
        const int drow = g * NNODES + (m < NNODES ? m : m - NNODES);
        const size_t dbase = (size_t)drow * Ka + (m < NNODES ? Nf : 2 * Nf) + nbase + lm;
        #pragma unroll
        for (int nf = 0; nf < 4; ++nf)
          Adst[dbase + nf * 16] = f2bf(acc[mf][nf][ri]);
      }
    }
  }
}

// ---------------- main split-K GEMM ----------------
// P[kc][row<400][Nn] = A[512 x BK-slice] @ bf16(W[BK-slice x BN-tile])
// BN=64: 512 blocks (16 kc x 32 nt), 72 KB LDS -> 2 blocks/CU for TLP.
template <int BN, int KA>
__global__ __launch_bounds__(512, 4)
void k_gemm(const float* __restrict__ W, const unsigned short* __restrict__ A,
            float* __restrict__ P, const int Nn, const int BK) {
  constexpr int NF = BN / 16;     // 16-col frags in tile
  constexpr int NFW = BN / 32;    // frags per wave (2-way wn split)
  constexpr int CW = BN / 16;     // W cols per thread
  __shared__ __align__(16) unsigned short Atile[MR * 64];          // 64 KB
  __shared__ __align__(16) unsigned short Wt[2 * NF * 64 * 8];     // ks x frag layout

  const int t = threadIdx.x;
  const int w = t >> 6, lane = t & 63;
  const int wm = w >> 1, wn = w & 1;
  const int lm = lane & 15;
  const int l4 = lane >> 4;
  const int kc = blockIdx.x & 15;
  const int nt = blockIdx.x >> 4;
  const int kbase = kc * BK;
  const int nbase = nt * BN;
  const int nks = BK >> 6;

  // ---- A staging geometry: chunk c -> lds byte c*8192 + t*16
  //      global row = c*64 + (t>>3); byte-in-row = (t*16 & 127) ^ ((row&7)<<4)
  const int arow0 = t >> 3;
  const int agb = ((t * 16) & 127) ^ ((arow0 & 7) << 4);
  const char* Ab = (const char*)A + (size_t)kbase * 2 + (size_t)arow0 * (KA * 2) + agb;
  const size_t CSTEP = (size_t)64 * KA * 2;

  // ---- W staging geometry: rows (kk0, kk0+1), cols colb..colb+CW-1
  const int kk0 = (t >> 4) * 2;
  const int colb = (t & 15) * CW;
  const float* Wg = W + (size_t)(kbase + kk0) * Nn + nbase + colb;
  int offWl[CW];
  {
    const int ks = kk0 >> 5, kg = (kk0 >> 3) & 3, jj1 = (kk0 & 7) >> 1;
    #pragma unroll
    for (int e = 0; e < CW; ++e) {
      const int nn = colb + e;
      const int nf = nn >> 4;
      const int ln = ((nn & 15) + 16 * kg) ^ (nf & 3);
      offWl[e] = ((ks * NF + nf) * 64 + ln) * 4 + jj1;
    }
  }

  // ---- fragment read bases ----
  const int aBase = (wm * 128 + lm) * 128 + ((l4 * 16) ^ ((lm & 7) << 4));
  int bAddr[NFW];
  #pragma unroll
  for (int nf = 0; nf < NFW; ++nf) {
    const int nfg = wn * NFW + nf;
    bAddr[nf] = ((nfg * 64) + (lane ^ (nfg & 3))) * 16;
  }
  constexpr int BSTRIDE = NF * 64 * 16;

  f32x4 acc[8][NFW];
  #pragma unroll
  for (int i = 0; i < 8; ++i)
    #pragma unroll
    for (int j = 0; j < NFW; ++j) acc[i][j] = (f32x4){0.f, 0.f, 0.f, 0.f};

  u32x4 areg[7];
  f32x4 w0_4, w1_4;
  f32x2 w0_2, w1_2;

  auto loadW = [&](int kt) {
    const float* p = Wg + (size_t)kt * 64 * Nn;
    if constexpr (BN == 64) {
      w0_4 = __builtin_nontemporal_load((const f32x4*)p);
      w1_4 = __builtin_nontemporal_load((const f32x4*)(p + Nn));
    } else {
      w0_2 = __builtin_nontemporal_load((const f32x2*)p);
      w1_2 = __builtin_nontemporal_load((const f32x2*)(p + Nn));
    }
  };
  auto storeW = [&]() {
    unsigned* w32 = (unsigned*)Wt;
    #pragma unroll
    for (int e = 0; e < CW; ++e) {
      if constexpr (BN == 64) w32[offWl[e]] = packbf(w0_4[e], w1_4[e]);
      else                    w32[offWl[e]] = packbf(w0_2[e], w1_2[e]);
    }
  };

  // prologue: stage kt=0 fully (8 A-chunks incl. permanent-zero rows 448..511)
  #pragma unroll
  for (int c = 0; c < 8; ++c) {
    u32x4 v = *(const u32x4*)(Ab + c * CSTEP);
    *(u32x4*)((char*)Atile + c * 8192 + t * 16) = v;
  }
  loadW(0);
  storeW();
  __syncthreads();

  for (int kt = 0; kt < nks; ++kt) {
    const bool more = (kt + 1 < nks);
    if (more) loadW(kt + 1);             // HBM stream: issue early
    // compute current tile
    #pragma unroll
    for (int ks = 0; ks < 2; ++ks) {
      short8 bfr[NFW];
      #pragma unroll
      for (int nf = 0; nf < NFW; ++nf)
        bfr[nf] = *(const short8*)((const char*)Wt + bAddr[nf] + ks * BSTRIDE);
      const int abx = aBase ^ (ks * 64);
      short8 af[8];
      #pragma unroll
      for (int mf = 0; mf < 8; ++mf)
        af[mf] = *(const short8*)((const char*)Atile + abx + mf * 2048);
      #pragma unroll
      for (int mf = 0; mf < 8; ++mf)
        #pragma unroll
        for (int nf = 0; nf < NFW; ++nf)
          acc[mf][nf] = __builtin_amdgcn_mfma_f32_16x16x32_bf16(af[mf], bfr[nf], acc[mf][nf], 0, 0, 0);
    }
    if (more) {                          // A from L2: issue late (keeps regs free in compute)
      #pragma unroll
      for (int c = 0; c < 7; ++c)
        areg[c] = *(const u32x4*)(Ab + c * CSTEP + (size_t)(kt + 1) * 128);
    }
    __syncthreads();
    if (more) {
      #pragma unroll
      for (int c = 0; c < 7; ++c)
        *(u32x4*)((char*)Atile + c * 8192 + t * 16) = areg[c];
      storeW();
    }
    __syncthreads();
  }

  // epilogue: P[kc][row][nbase+col]
  float* Pk = P + ((size_t)kc * PV) * Nn + nbase;
  #pragma unroll
  for (int mf = 0; mf < 8; ++mf) {
    const int row0 = wm * 128 + mf * 16 + l4 * 4;
    #pragma unroll
    for (int ri = 0; ri < 4; ++ri) {
      const int row = row0 + ri;
      if (row < MV) {
        #pragma unroll
        for (int nf = 0; nf < NFW; ++nf) {
          const int col = (wn * NFW + nf) * 16 + lm;
          __builtin_nontemporal_store(acc[mf][nf][ri], Pk + (size_t)row * Nn + col);
        }
      }
    }
  }
}

// H = relu(sum_kc P1 + b1) -> bf16 into A2 T0 region
__global__ void k_ep1(const float* __restrict__ P1, const float* __restrict__ b1,
                      unsigned short* __restrict__ A2) {
  int gid = blockIdx.x * 256 + threadIdx.x;
  int row = gid / (NH / 4);
  int c = (gid % (NH / 4)) * 4;
  f32x4 s = {0.f, 0.f, 0.f, 0.f};
  #pragma unroll
  for (int kc = 0; kc < KC1; ++kc)
    s += __builtin_nontemporal_load((const f32x4*)(P1 + ((size_t)kc * PV + row) * NH + c));
  const f32x4 b = *(const f32x4*)(b1 + c);
  unsigned long long pack = 0;
  #pragma unroll
  for (int i = 0; i < 4; ++i) {
    float v = s[i] + b[i];
    pack |= (unsigned long long)f2bf(v > 0.f ? v : 0.f) << (16 * i);
  }
  *(unsigned long long*)(A2 + (size_t)row * K2 + c) = pack;
}

// ---------------- classifier input: zt[g][r][j] = sum_kc P2 + b2[r] (transposed) ----------------
__global__ __launch_bounds__(256)
void k_zsum(const float* __restrict__ P2, const float* __restrict__ b2,
            float* __restrict__ zt) {
  __shared__ float tile[8][520];
  const int g = blockIdx.x / 25;
  const int j0 = (blockIdx.x % 25) * 8;
  const int t = threadIdx.x;
  const int j = t >> 5;
  const int c0 = (t & 31) * 16;
  const int row = g * NNODES + j0 + j;

  #pragma unroll
  for (int ci = 0; ci < 4; ++ci) {
    const int c = c0 + ci * 4;
    f32x4 s = *(const f32x4*)(b2 + c);
    #pragma unroll
    for (int kc = 0; kc < KC2; ++kc)
      s += __builtin_nontemporal_load((const f32x4*)(P2 + ((size_t)kc * PV + row) * NCL + c));
    *(f32x4*)&tile[j][c] = s;
  }
  __syncthreads();

  #pragma unroll
  for (int ci = 0; ci < 2; ++ci) {
    const int c = ci * 256 + t;
    f32x4 lo, hi;
    #pragma unroll
    for (int e = 0; e < 4; ++e) { lo[e] = tile[e][c]; hi[e] = tile[4 + e][c]; }
    float* zr = zt + ((size_t)g * NCL + c) * 200 + j0;
    *(f32x4*)zr = lo;
    *(f32x4*)(zr + 4) = hi;
  }
}

// ---------------- fused 3-layer classifier, one wave per output row ----------------
__global__ __launch_bounds__(256)
void k_cls2(const float* __restrict__ zt,
            const float* __restrict__ Wc1, const float* __restrict__ bc1,
            const float* __restrict__ Wc2, const float* __restrict__ bc2,
            const float* __restrict__ Wc3, const float* __restrict__ bc3,
            float* __restrict__ outp) {
  __shared__ float zs[4][200];
  __shared__ float h1s[4][100];
  __shared__ float h2s[4][50];
  const int g = blockIdx.x >> 7;
  const int t = threadIdx.x;
  const int w = t >> 6, lane = t & 63;
  const int r = (blockIdx.x & 127) * 4 + w;

  const float* zr = zt + ((size_t)g * NCL + r) * 200;
  #pragma unroll
  for (int i = 0; i < 4; ++i) {
    const int idx = i * 64 + lane;
    if (idx < 200) zs[w][idx] = zr[idx];
  }
  __syncthreads();

  {
    const int c0 = lane;
    const int c1 = lane + 64;
    const int c1m = (c1 < 100) ? c1 : 99;
    float a0 = bc1[c0 < 100 ? c0 : 99];
    float a1 = bc1[c1m];
    const float* w0 = Wc1 + c0 * 200;
    const float* w1 = Wc1 + c1m * 200;
    #pragma unroll 8
    for (int j = 0; j < 200; ++j) {
      const float zv = zs[w][j];
      a0 = fmaf(zv, w0[j], a0);
      a1 = fmaf(zv, w1[j], a1);
    }
    if (c0 < 100) h1s[w][c0] = a0 > 0.f ? a0 : 0.f;
    if (c1 < 100) h1s[w][c1] = a1 > 0.f ? a1 : 0.f;
  }
  __syncthreads();

  {
    const int c2 = (lane < 50) ? lane : 49;
    float b = bc2[c2];
    const float* w2 = Wc2 + c2 * 100;
    #pragma unroll 10
    for (int c = 0; c < 100; ++c) b = fmaf(h1s[w][c], w2[c], b);
    if (lane < 50) h2s[w][lane] = b > 0.f ? b : 0.f;
  }
  __syncthreads();

  {
    float v = (lane < 50) ? h2s[w][lane] * Wc3[lane] : 0.f;
    #pragma unroll
    for (int off = 32; off >= 1; off >>= 1) v += __shfl_down(v, off);
    if (lane == 0) outp[g * NCL + r] = v + bc3[0];
  }
}

extern "C" void kernel_launch(void* const* d_in, const int* in_sizes, int n_in,
                              void* d_out, int out_size, void* d_ws, size_t ws_size,
                              hipStream_t stream) {
  const float* x1  = (const float*)d_in[0];
  const int*   ei1 = (const int*)d_in[1];
  const float* ea1 = (const float*)d_in[2];
  const float* x2  = (const float*)d_in[3];
  const int*   ei2 = (const int*)d_in[4];
  const float* ea2 = (const float*)d_in[5];
  const float* W1  = (const float*)d_in[6];
  const float* b1  = (const float*)d_in[7];
  const float* W2  = (const float*)d_in[8];
  const float* b2  = (const float*)d_in[9];
  const float* Wc1 = (const float*)d_in[10];
  const float* bc1 = (const float*)d_in[11];
  const float* Wc2 = (const float*)d_in[12];
  const float* bc2 = (const float*)d_in[13];
  const float* Wc3 = (const float*)d_in[14];
  const float* bc3 = (const float*)d_in[15];
  float* outp = (float*)d_out;

  char* ws = (char*)d_ws;
  float*          P1  = (float*)(ws + OFF_P1);
  float*          P2  = (float*)(ws + OFF_P2);
  unsigned short* A1  = (unsigned short*)(ws + OFF_A1);
  unsigned short* A2  = (unsigned short*)(ws + OFF_A2);
  float*          deg = (float*)(ws + OFF_DEG);
  float*          Ld  = (float*)(ws + OFF_LD);
  unsigned short* LLb = (unsigned short*)(ws + OFF_LL);
  float*          zt  = (float*)(ws + OFF_Z);

  k_zero<<<1871, 256, 0, stream>>>(
      (f32x4*)(ws + OFF_DEG), 48800,
      (f32x4*)(ws + OFF_A1 + (size_t)MV * K1 * 2), 344064,
      (f32x4*)(ws + OFF_A2 + (size_t)MV * K2 * 2), 86016);

  k_deg<<<63, 256, 0, stream>>>(ei1, ea1, ei2, ea2, deg);
  k_buildL<<<63, 256, 0, stream>>>(ei1, ea1, ei2, ea2, deg, Ld);
  k_LL<<<400, 256, 0, stream>>>(Ld, LLb);
  k_t0<<<1600, 256, 0, stream>>>(x1, x2, A1);
  k_abuild<<<(NF1 / 64) * 2, 256, 0, stream>>>(LLb, A1, A1, NF1, K1);
  k_gemm<64, K1><<<KC1 * (NH / 64), 512, 0, stream>>>(W1, A1, P1, NH, BK1);
  k_ep1<<<800, 256, 0, stream>>>(P1, b1, A2);
  k_abuild<<<(NH / 64) * 2, 256, 0, stream>>>(LLb, A2, A2, NH, K2);
  k_gemm<32, K2><<<KC2 * (NCL / 32), 512, 0, stream>>>(W2, A2, P2, NCL, BK2);
  k_zsum<<<50, 256, 0, stream>>>(P2, b2, zt);
  k_cls2<<<256, 256, 0, stream>>>(zt, Wc1, bc1, Wc2, bc2, Wc3, bc3, outp);
}

// Round 6
// 177.050 us; speedup vs baseline: 1.2095x; 1.2095x over previous
//
#include <hip/hip_runtime.h>

typedef __attribute__((ext_vector_type(8))) short short8;
typedef __attribute__((ext_vector_type(4))) float f32x4;
typedef __attribute__((ext_vector_type(2))) float f32x2;
typedef __attribute__((ext_vector_type(4))) unsigned int u32x4;

#define NNODES 200
#define NEDGE  8000
#define NF1    8192
#define NH     2048
#define NCL    512
#define K1     24576
#define K2     6144
#define MR     448      // padded rows (2 graphs * 200 -> 400 valid), 448 = 4 waves * 7 frags * 16
#define MV     400
#define PV     400      // P partial row stride (valid rows only)
#define KC1    16
#define BK1    1536
#define KC2    16
#define BK2    384

// ---------------- workspace layout (bytes) ----------------
#define OFF_P1  0ull
#define SZ_P1   (16ull*PV*NH*4)            // 52,428,800
#define OFF_P2  (OFF_P1 + SZ_P1)
#define SZ_P2   (16ull*PV*NCL*4)           // 13,107,200
#define OFF_A1  (OFF_P2 + SZ_P2)           // 65,536,000
#define SZ_A1   ((unsigned long long)MR*K1*2)  // 22,020,096
#define OFF_A2  (OFF_A1 + SZ_A1)           // 87,556,096
#define SZ_A2   ((unsigned long long)MR*K2*2)  // 5,505,024
#define OFF_DEG (OFF_A2 + SZ_A2)           // 93,061,120
#define OFF_LD  (OFF_DEG + 2048)
#define OFF_LL  (OFF_LD + 320000ull)       // LL: 2*448*224*2 = 401,408  (end ~89.5MB)
// zt (classifier input, 2*512*200*4 = 819,200 B) reuses the P1 region (dead by then)
#define OFF_Z   OFF_P1

static __device__ __forceinline__ unsigned short f2bf(float f) {
  unsigned int u = __float_as_uint(f);
  unsigned int r = (u + 0x7fffu + ((u >> 16) & 1u)) >> 16;
  return (unsigned short)r;
}
static __device__ __forceinline__ unsigned packbf(float a, float b) {
  return (unsigned)f2bf(a) | ((unsigned)f2bf(b) << 16);
}

// ---------------- zero scratch regions ----------------
__global__ void k_zero(f32x4* p1, int n1, f32x4* p2, int n2, f32x4* p3, int n3) {
  int i = blockIdx.x * 256 + threadIdx.x;
  f32x4 z = {0.f, 0.f, 0.f, 0.f};
  if (i < n1) p1[i] = z;
  i -= n1;
  if (i >= 0 && i < n2) p2[i] = z;
  i -= n2;
  if (i >= 0 && i < n3) p3[i] = z;
}

__global__ void k_deg(const int* __restrict__ ei1, const float* __restrict__ ew1,
                      const int* __restrict__ ei2, const float* __restrict__ ew2,
                      float* __restrict__ deg) {
  int e = blockIdx.x * 256 + threadIdx.x;
  if (e >= 2 * NEDGE) return;
  int g = e / NEDGE, k = e % NEDGE;
  const int* ei = g ? ei2 : ei1;
  const float* ew = g ? ew2 : ew1;
  atomicAdd(deg + g * NNODES + ei[k], ew[k]);
}

__global__ void k_buildL(const int* __restrict__ ei1, const float* __restrict__ ew1,
                         const int* __restrict__ ei2, const float* __restrict__ ew2,
                         const float* __restrict__ deg, float* __restrict__ Ld) {
  int e = blockIdx.x * 256 + threadIdx.x;
  if (e >= 2 * NEDGE) return;
  int g = e / NEDGE, k = e % NEDGE;
  const int* ei = g ? ei2 : ei1;
  const float* ew = g ? ew2 : ew1;
  int r = ei[k], c = ei[NEDGE + k];
  float dr = deg[g * NNODES + r], dc = deg[g * NNODES + c];
  float ir = dr > 0.f ? 1.0f / sqrtf(dr) : 0.f;
  float ic = dc > 0.f ? 1.0f / sqrtf(dc) : 0.f;
  float nrm = -ir * ew[k] * ic;
  atomicAdd(Ld + ((size_t)g * NNODES + c) * NNODES + r, nrm);
}

// LL rows [0,200): L ; rows [200,400): 2L^2-I   (bf16, stride 224, 448-row panels)
__global__ void k_LL(const float* __restrict__ Ld, unsigned short* __restrict__ LLb) {
  int b = blockIdx.x;
  int g = b / NNODES, i = b % NNODES;
  __shared__ float Lr[NNODES];
  const float* Lg = Ld + (size_t)g * NNODES * NNODES;
  int t = threadIdx.x;
  if (t < NNODES) Lr[t] = Lg[i * NNODES + t];
  __syncthreads();
  if (t < NNODES) {
    float acc = 0.f;
    for (int k = 0; k < NNODES; ++k) acc = fmaf(Lr[k], Lg[k * NNODES + t], acc);
    unsigned short* LLg = LLb + (size_t)g * MR * 224;
    LLg[(size_t)i * 224 + t] = f2bf(Lr[t]);
    LLg[(size_t)(NNODES + i) * 224 + t] = f2bf(2.f * acc - (i == t ? 1.f : 0.f));
  }
}

__global__ void k_t0(const float* __restrict__ x1, const float* __restrict__ x2,
                     unsigned short* __restrict__ A1) {
  int gid = blockIdx.x * 256 + threadIdx.x;
  int row = gid / (NF1 / 8);
  int c8 = (gid % (NF1 / 8)) * 8;
  const float* xp = (row < NNODES ? x1 + (size_t)row * NF1
                                  : x2 + (size_t)(row - NNODES) * NF1) + c8;
  f32x4 a = *(const f32x4*)xp;
  f32x4 b = *(const f32x4*)(xp + 4);
  u32x4 o;
  o[0] = packbf(a[0], a[1]);
  o[1] = packbf(a[2], a[3]);
  o[2] = packbf(b[0], b[1]);
  o[3] = packbf(b[2], b[3]);
  *(u32x4*)(A1 + (size_t)row * K1 + c8) = o;
}

// builds T1/T2 column blocks:  [T1;T2](:, nt*64..) = LL @ T0(:, nt*64..)
__global__ __launch_bounds__(256, 1)
void k_abuild(const unsigned short* __restrict__ LLb, const unsigned short* __restrict__ Asrc,
              unsigned short* __restrict__ Adst, const int Nf, const int Ka) {
  __shared__ __align__(16) unsigned short XF[7][4][64][8];
  const int g = blockIdx.x & 1;
  const int nt = blockIdx.x >> 1;
  const int nbase = nt * 64;
  const int t = threadIdx.x;

  #pragma unroll
  for (int it = 0; it < 14; ++it) {
    const int pos = it * 256 + t;
    const int j = pos >> 4;
    const int n4 = (pos & 15) * 4;
    unsigned long long v = 0ull;
    if (j < NNODES)
      v = *(const unsigned long long*)(Asrc + (size_t)(g * NNODES + j) * Ka + nbase + n4);
    const int ks = j >> 5, kg = (j >> 3) & 3, jj = j & 7;
    #pragma unroll
    for (int e = 0; e < 4; ++e) {
      const int nn = n4 + e;
      XF[ks][nn >> 4][(nn & 15) + 16 * kg][jj] = (unsigned short)(v >> (16 * e));
    }
  }
  __syncthreads();

  const int w = t >> 6, lane = t & 63;
  const int lm = lane & 15, lk8 = (lane >> 4) * 8;
  f32x4 acc[7][4];
  #pragma unroll
  for (int i = 0; i < 7; ++i)
    #pragma unroll
    for (int j = 0; j < 4; ++j) acc[i][j] = (f32x4){0.f, 0.f, 0.f, 0.f};

  const unsigned short* LLg = LLb + (size_t)g * MR * 224;
  #pragma unroll
  for (int ks = 0; ks < 7; ++ks) {
    short8 bfr[4];
    #pragma unroll
    for (int nf = 0; nf < 4; ++nf) bfr[nf] = *(const short8*)&XF[ks][nf][lane][0];
    short8 af[7];
    #pragma unroll
    for (int mf = 0; mf < 7; ++mf)
      af[mf] = *(const short8*)(LLg + (size_t)(w * 112 + mf * 16 + lm) * 224 + ks * 32 + lk8);
    #pragma unroll
    for (int mf = 0; mf < 7; ++mf)
      #pragma unroll
      for (int nf = 0; nf < 4; ++nf)
        acc[mf][nf] = __builtin_amdgcn_mfma_f32_16x16x32_bf16(af[mf], bfr[nf], acc[mf][nf], 0, 0, 0);
  }

  const int lr4 = (lane >> 4) * 4;
  #pragma unroll
  for (int mf = 0; mf < 7; ++mf) {
    #pragma unroll
    for (int ri = 0; ri < 4; ++ri) {
      const int m = w * 112 + mf * 16 + lr4 + ri;
      if (m < MV) {
        const int drow = g * NNODES + (m < NNODES ? m : m - NNODES);
        const size_t dbase = (size_t)drow * Ka + (m < NNODES ? Nf : 2 * Nf) + nbase + lm;
        #pragma unroll
        for (int nf = 0; nf < 4; ++nf)
          Adst[dbase + nf * 16] = f2bf(acc[mf][nf][ri]);
      }
    }
  }
}

// ---------------- main split-K GEMM, full LDS double-buffer, 1 barrier/k-step ----------------
// P[kc][row<400][Nn] = A[448 x BK-slice] @ bf16(W[BK-slice x BN-tile])
template <int BN, int KA>
__global__ __launch_bounds__(512, 2)
void k_gemm(const float* __restrict__ W, const unsigned short* __restrict__ A,
            float* __restrict__ P, const int Nn, const int BK) {
  constexpr int NF = BN / 16;       // 16-col frags in tile
  constexpr int NFW = BN / 32;      // frags per wave (2-way wn split)
  constexpr int CW = BN / 16;       // W cols per thread (x2 rows)
  constexpr int ABUF = MR * 128;    // bytes per A buffer (448 rows x 128 B)
  constexpr int BSTRIDE = NF * 1024; // ks=1 byte stride in a W buffer
  constexpr int WBUF = 2 * BSTRIDE;  // bytes per W buffer
  __shared__ __align__(16) unsigned short Atile[2 * MR * 64];   // 114,688 B
  __shared__ __align__(16) unsigned short Wt[2 * NF * 1024];    // 2 x WBUF bytes

  const int t = threadIdx.x;
  const int w = t >> 6, lane = t & 63;
  const int wm = w >> 1, wn = w & 1;
  const int lm = lane & 15;
  const int l4 = lane >> 4;
  const int kc = blockIdx.x & 15;
  const int nt = blockIdx.x >> 4;
  const int kbase = kc * BK;
  const int nbase = nt * BN;
  const int nks = BK >> 6;

  // ---- A staging: chunk c (7 chunks of 64 rows) -> lds byte buf*ABUF + c*8192 + t*16
  const int arow0 = t >> 3;
  const int agb = ((t * 16) & 127) ^ ((arow0 & 7) << 4);
  const char* Ab = (const char*)A + (size_t)kbase * 2 + (size_t)arow0 * (KA * 2) + agb;
  const size_t CSTEP = (size_t)64 * KA * 2;

  // ---- W staging: rows (kk0, kk0+1), cols colb..colb+CW-1
  const int kk0 = (t >> 4) * 2;
  const int colb = (t & 15) * CW;
  const float* Wg = W + (size_t)(kbase + kk0) * Nn + nbase + colb;
  int offWl[CW];   // u32 index within one W buffer
  {
    const int ks0 = kk0 >> 5, kg0 = (kk0 >> 3) & 3, jj1 = (kk0 & 7) >> 1;
    #pragma unroll
    for (int e = 0; e < CW; ++e) {
      const int nn = colb + e;
      const int nf = nn >> 4;
      const int ln = ((nn & 15) + 16 * kg0) ^ (nf & 3);
      offWl[e] = ((ks0 * NF + nf) * 64 + ln) * 4 + jj1;
    }
  }

  // ---- fragment read bases ----
  const int aBase = (wm * 112 + lm) * 128 + ((l4 * 16) ^ ((lm & 7) << 4));
  int bAddr[NFW];
  #pragma unroll
  for (int nf = 0; nf < NFW; ++nf) {
    const int nfg = wn * NFW + nf;
    bAddr[nf] = nfg * 1024 + (lane ^ (nfg & 3)) * 16;
  }

  f32x4 acc[7][NFW];
  #pragma unroll
  for (int i = 0; i < 7; ++i)
    #pragma unroll
    for (int j = 0; j < NFW; ++j) acc[i][j] = (f32x4){0.f, 0.f, 0.f, 0.f};

  u32x4 areg[7];
  f32x4 w0a, w0b, w1a, w1b;
  f32x2 w0s, w1s;

  auto loadW = [&](int kt) {
    const float* p = Wg + (size_t)kt * 64 * Nn;
    if constexpr (BN == 128) {
      w0a = __builtin_nontemporal_load((const f32x4*)p);
      w0b = __builtin_nontemporal_load((const f32x4*)(p + 4));
      w1a = __builtin_nontemporal_load((const f32x4*)(p + Nn));
      w1b = __builtin_nontemporal_load((const f32x4*)(p + Nn + 4));
    } else {
      w0s = __builtin_nontemporal_load((const f32x2*)p);
      w1s = __builtin_nontemporal_load((const f32x2*)(p + Nn));
    }
  };
  auto loadA = [&](int kt) {
    #pragma unroll
    for (int c = 0; c < 7; ++c)
      areg[c] = *(const u32x4*)(Ab + c * CSTEP + (size_t)kt * 128);
  };
  auto storeA = [&](int buf) {
    #pragma unroll
    for (int c = 0; c < 7; ++c)
      *(u32x4*)((char*)Atile + buf * ABUF + c * 8192 + t * 16) = areg[c];
  };
  auto storeW = [&](int buf) {
    unsigned* w32 = (unsigned*)Wt + buf * (WBUF / 4);
    #pragma unroll
    for (int e = 0; e < CW; ++e) {
      float lo, hi;
      if constexpr (BN == 128) {
        lo = (e < 4) ? w0a[e & 3] : w0b[e & 3];
        hi = (e < 4) ? w1a[e & 3] : w1b[e & 3];
      } else {
        lo = w0s[e & 1];
        hi = w1s[e & 1];
      }
      w32[offWl[e]] = packbf(lo, hi);
    }
  };

  // prologue: stage kt=0 into buf 0
  loadW(0);
  loadA(0);
  storeA(0);
  storeW(0);
  __syncthreads();

  for (int kt = 0; kt < nks; ++kt) {
    const int buf = kt & 1;
    const bool more = (kt + 1 < nks);
    if (more) loadW(kt + 1);           // HBM long pole: issue first

    #pragma unroll
    for (int ks = 0; ks < 2; ++ks) {
      short8 bfr[NFW];
      #pragma unroll
      for (int nf = 0; nf < NFW; ++nf)
        bfr[nf] = *(const short8*)((const char*)Wt + buf * WBUF + bAddr[nf] + ks * BSTRIDE);
      const int abx = (aBase ^ (ks * 64)) + buf * ABUF;
      short8 af[7];
      #pragma unroll
      for (int mf = 0; mf < 7; ++mf)
        af[mf] = *(const short8*)((const char*)Atile + abx + mf * 2048);
      #pragma unroll
      for (int mf = 0; mf < 7; ++mf)
        #pragma unroll
        for (int nf = 0; nf < NFW; ++nf)
          acc[mf][nf] = __builtin_amdgcn_mfma_f32_16x16x32_bf16(af[mf], bfr[nf], acc[mf][nf], 0, 0, 0);
      if (ks == 0 && more) loadA(kt + 1);   // L2 loads mid-compute
    }

    if (more) {
      storeA(buf ^ 1);
      storeW(buf ^ 1);
    }
    __syncthreads();   // vmcnt drain free: all loads already consumed by stores
  }

  // epilogue: P[kc][row][nbase+col]
  float* Pk = P + ((size_t)kc * PV) * Nn + nbase;
  #pragma unroll
  for (int mf = 0; mf < 7; ++mf) {
    const int row0 = wm * 112 + mf * 16 + l4 * 4;
    #pragma unroll
    for (int ri = 0; ri < 4; ++ri) {
      const int row = row0 + ri;
      if (row < MV) {
        #pragma unroll
        for (int nf = 0; nf < NFW; ++nf) {
          const int col = (wn * NFW + nf) * 16 + lm;
          __builtin_nontemporal_store(acc[mf][nf][ri], Pk + (size_t)row * Nn + col);
        }
      }
    }
  }
}

// H = relu(sum_kc P1 + b1) -> bf16 into A2 T0 region
__global__ void k_ep1(const float* __restrict__ P1, const float* __restrict__ b1,
                      unsigned short* __restrict__ A2) {
  int gid = blockIdx.x * 256 + threadIdx.x;
  int row = gid / (NH / 4);
  int c = (gid % (NH / 4)) * 4;
  f32x4 s = {0.f, 0.f, 0.f, 0.f};
  #pragma unroll
  for (int kc = 0; kc < KC1; ++kc)
    s += __builtin_nontemporal_load((const f32x4*)(P1 + ((size_t)kc * PV + row) * NH + c));
  const f32x4 b = *(const f32x4*)(b1 + c);
  unsigned long long pack = 0;
  #pragma unroll
  for (int i = 0; i < 4; ++i) {
    float v = s[i] + b[i];
    pack |= (unsigned long long)f2bf(v > 0.f ? v : 0.f) << (16 * i);
  }
  *(unsigned long long*)(A2 + (size_t)row * K2 + c) = pack;
}

// ---------------- classifier input: zt[g][r][j] = sum_kc P2 + b2[r] (transposed) ----------------
// grid: 2 graphs * 25 j-tiles * 2 col-halves = 100 blocks
__global__ __launch_bounds__(256)
void k_zsum(const float* __restrict__ P2, const float* __restrict__ b2,
            float* __restrict__ zt) {
  __shared__ float tile[8][264];
  const int b = blockIdx.x;
  const int g = b / 50;
  const int r2 = b % 50;
  const int j0 = (r2 >> 1) * 8;
  const int ch = (r2 & 1) * 256;
  const int t = threadIdx.x;
  const int j = t >> 5;
  const int c0 = (t & 31) * 8;
  const int row = g * NNODES + j0 + j;

  #pragma unroll
  for (int ci = 0; ci < 2; ++ci) {
    const int c = c0 + ci * 4;
    f32x4 s = *(const f32x4*)(b2 + ch + c);
    #pragma unroll
    for (int kc = 0; kc < KC2; ++kc)
      s += __builtin_nontemporal_load((const f32x4*)(P2 + ((size_t)kc * PV + row) * NCL + ch + c));
    *(f32x4*)&tile[j][c] = s;
  }
  __syncthreads();

  f32x4 lo, hi;
  #pragma unroll
  for (int e = 0; e < 4; ++e) { lo[e] = tile[e][t]; hi[e] = tile[4 + e][t]; }
  float* zr = zt + ((size_t)g * NCL + ch + t) * 200 + j0;
  *(f32x4*)zr = lo;
  *(f32x4*)(zr + 4) = hi;
}

// ---------------- fused 3-layer classifier, one wave per output row ----------------
__global__ __launch_bounds__(256)
void k_cls2(const float* __restrict__ zt,
            const float* __restrict__ Wc1, const float* __restrict__ bc1,
            const float* __restrict__ Wc2, const float* __restrict__ bc2,
            const float* __restrict__ Wc3, const float* __restrict__ bc3,
            float* __restrict__ outp) {
  __shared__ float zs[4][200];
  __shared__ float h1s[4][100];
  __shared__ float h2s[4][50];
  const int g = blockIdx.x >> 7;
  const int t = threadIdx.x;
  const int w = t >> 6, lane = t & 63;
  const int r = (blockIdx.x & 127) * 4 + w;

  const float* zr = zt + ((size_t)g * NCL + r) * 200;
  #pragma unroll
  for (int i = 0; i < 4; ++i) {
    const int idx = i * 64 + lane;
    if (idx < 200) zs[w][idx] = zr[idx];
  }
  __syncthreads();

  {
    const int c0 = lane;
    const int c1 = lane + 64;
    const int c1m = (c1 < 100) ? c1 : 99;
    float a0 = bc1[c0 < 100 ? c0 : 99];
    float a1 = bc1[c1m];
    const float* w0 = Wc1 + c0 * 200;
    const float* w1 = Wc1 + c1m * 200;
    #pragma unroll 8
    for (int j = 0; j < 200; ++j) {
      const float zv = zs[w][j];
      a0 = fmaf(zv, w0[j], a0);
      a1 = fmaf(zv, w1[j], a1);
    }
    if (c0 < 100) h1s[w][c0] = a0 > 0.f ? a0 : 0.f;
    if (c1 < 100) h1s[w][c1] = a1 > 0.f ? a1 : 0.f;
  }
  __syncthreads();

  {
    const int c2 = (lane < 50) ? lane : 49;
    float b = bc2[c2];
    const float* w2 = Wc2 + c2 * 100;
    #pragma unroll 10
    for (int c = 0; c < 100; ++c) b = fmaf(h1s[w][c], w2[c], b);
    if (lane < 50) h2s[w][lane] = b > 0.f ? b : 0.f;
  }
  __syncthreads();

  {
    float v = (lane < 50) ? h2s[w][lane] * Wc3[lane] : 0.f;
    #pragma unroll
    for (int off = 32; off >= 1; off >>= 1) v += __shfl_down(v, off);
    if (lane == 0) outp[g * NCL + r] = v + bc3[0];
  }
}

extern "C" void kernel_launch(void* const* d_in, const int* in_sizes, int n_in,
                              void* d_out, int out_size, void* d_ws, size_t ws_size,
                              hipStream_t stream) {
  const float* x1  = (const float*)d_in[0];
  const int*   ei1 = (const int*)d_in[1];
  const float* ea1 = (const float*)d_in[2];
  const float* x2  = (const float*)d_in[3];
  const int*   ei2 = (const int*)d_in[4];
  const float* ea2 = (const float*)d_in[5];
  const float* W1  = (const float*)d_in[6];
  const float* b1  = (const float*)d_in[7];
  const float* W2  = (const float*)d_in[8];
  const float* b2  = (const float*)d_in[9];
  const float* Wc1 = (const float*)d_in[10];
  const float* bc1 = (const float*)d_in[11];
  const float* Wc2 = (const float*)d_in[12];
  const float* bc2 = (const float*)d_in[13];
  const float* Wc3 = (const float*)d_in[14];
  const float* bc3 = (const float*)d_in[15];
  float* outp = (float*)d_out;

  char* ws = (char*)d_ws;
  float*          P1  = (float*)(ws + OFF_P1);
  float*          P2  = (float*)(ws + OFF_P2);
  unsigned short* A1  = (unsigned short*)(ws + OFF_A1);
  unsigned short* A2  = (unsigned short*)(ws + OFF_A2);
  float*          deg = (float*)(ws + OFF_DEG);
  float*          Ld  = (float*)(ws + OFF_LD);
  unsigned short* LLb = (unsigned short*)(ws + OFF_LL);
  float*          zt  = (float*)(ws + OFF_Z);

  // zero: [deg|Ld|LL] (723,456 B) + A1 pad rows (400..447) + A2 pad rows
  k_zero<<<897, 256, 0, stream>>>(
      (f32x4*)(ws + OFF_DEG), 45216,
      (f32x4*)(ws + OFF_A1 + (size_t)MV * K1 * 2), 147456,
      (f32x4*)(ws + OFF_A2 + (size_t)MV * K2 * 2), 36864);

  k_deg<<<63, 256, 0, stream>>>(ei1, ea1, ei2, ea2, deg);
  k_buildL<<<63, 256, 0, stream>>>(ei1, ea1, ei2, ea2, deg, Ld);
  k_LL<<<400, 256, 0, stream>>>(Ld, LLb);
  k_t0<<<1600, 256, 0, stream>>>(x1, x2, A1);
  k_abuild<<<(NF1 / 64) * 2, 256, 0, stream>>>(LLb, A1, A1, NF1, K1);
  k_gemm<128, K1><<<KC1 * (NH / 128), 512, 0, stream>>>(W1, A1, P1, NH, BK1);
  k_ep1<<<800, 256, 0, stream>>>(P1, b1, A2);
  k_abuild<<<(NH / 64) * 2, 256, 0, stream>>>(LLb, A2, A2, NH, K2);
  k_gemm<32, K2><<<KC2 * (NCL / 32), 512, 0, stream>>>(W2, A2, P2, NCL, BK2);
  k_zsum<<<100, 256, 0, stream>>>(P2, b2, zt);
  k_cls2<<<256, 256, 0, stream>>>(zt, Wc1, bc1, Wc2, bc2, Wc3, bc3, outp);
}